// Round 8
// baseline (315.894 us; speedup 1.0000x reference)
//
#include <hip/hip_runtime.h>
#include <math.h>

#define CDIM 256
#define QKVDIM 768
#define NHEADS 8
#define DHEAD 32
#define NWIN 7
#define NREG 49
#define TK 4
static constexpr int NROWS = 8 * 56 * 56;  // 25088

typedef __attribute__((ext_vector_type(8))) short s16x8;
typedef __attribute__((ext_vector_type(4))) float f32x4;
typedef __attribute__((ext_vector_type(16))) float f32x16;
typedef unsigned short ushort_t;

union U4 { unsigned u[4]; s16x8 v; };

__device__ __forceinline__ ushort_t bfr(float f) {  // fp32 -> bf16 RNE
    unsigned u = __float_as_uint(f);
    unsigned r = (u + 0x7FFFu + ((u >> 16) & 1u)) >> 16;
    return (ushort_t)r;
}
__device__ __forceinline__ float gelu_f(float x) {
    float u = 0.7978845608028654f * (x + 0.044715f * x * x * x);
    float e = __expf(2.0f * u);                 // tanh(u) = 1 - 2/(e^{2u}+1)
    float t = 1.0f - __fdividef(2.0f, e + 1.0f);
    return 0.5f * x * (1.0f + t);
}
__device__ __forceinline__ void glds16(const void* g, void* l) {
    __builtin_amdgcn_global_load_lds((const __attribute__((address_space(1))) void*)g,
                                     (__attribute__((address_space(3))) void*)l, 16, 0, 0);
}
template <int N>
__device__ __forceinline__ void waitvm() {
    if constexpr (N == 0) asm volatile("s_waitcnt vmcnt(0)" ::: "memory");
    else if constexpr (N == 3) asm volatile("s_waitcnt vmcnt(3)" ::: "memory");
    else if constexpr (N == 4) asm volatile("s_waitcnt vmcnt(4)" ::: "memory");
    else if constexpr (N == 6) asm volatile("s_waitcnt vmcnt(6)" ::: "memory");
    else if constexpr (N == 8) asm volatile("s_waitcnt vmcnt(8)" ::: "memory");
}
__device__ __forceinline__ void barrier_raw() {
    asm volatile("s_barrier" ::: "memory");
}
__device__ __forceinline__ f32x16 zero16() {
    f32x16 z;
#pragma unroll
    for (int i = 0; i < 16; i++) z[i] = 0.f;
    return z;
}

// ---------------- LayerNorm: fp32 in -> bf16 out. one wave per row ----------------
__global__ __launch_bounds__(256) void ln_kernel(const float* __restrict__ x,
                                                 const float* __restrict__ g,
                                                 const float* __restrict__ bparam,
                                                 ushort_t* __restrict__ y) {
    int wave = threadIdx.x >> 6, lane = threadIdx.x & 63;
    int row = blockIdx.x * 4 + wave;
    const float4* xr = (const float4*)(x + (size_t)row * CDIM);
    float4 v = xr[lane];
    float s = v.x + v.y + v.z + v.w;
    float s2 = v.x * v.x + v.y * v.y + v.z * v.z + v.w * v.w;
#pragma unroll
    for (int off = 32; off; off >>= 1) {
        s += __shfl_xor(s, off, 64);
        s2 += __shfl_xor(s2, off, 64);
    }
    float mu = s * (1.0f / CDIM);
    float rstd = rsqrtf(s2 * (1.0f / CDIM) - mu * mu + 1e-5f);
    float4 gv = ((const float4*)g)[lane];
    float4 bv = ((const float4*)bparam)[lane];
    ushort4 o;
    o.x = bfr((v.x - mu) * rstd * gv.x + bv.x);
    o.y = bfr((v.y - mu) * rstd * gv.y + bv.y);
    o.z = bfr((v.z - mu) * rstd * gv.z + bv.z);
    o.w = bfr((v.w - mu) * rstd * gv.w + bv.w);
    *(ushort4*)(y + (size_t)row * CDIM + lane * 4) = o;
}

// ---------------- f32 region means of LN1(x): ymean[b*49+r][256] ----------------
__global__ __launch_bounds__(256) void ymean_kernel(const float* __restrict__ x,
                                                    const float* __restrict__ g,
                                                    const float* __restrict__ bparam,
                                                    float* __restrict__ ymean) {
    int blk = blockIdx.x;  // b*49 + rid
    int b = blk / NREG, rid = blk % NREG;
    int ai = rid / NWIN, aj = rid % NWIN;
    int w = threadIdx.x >> 6, lane = threadIdx.x & 63;
    float4 gv = ((const float4*)g)[lane];
    float4 bv = ((const float4*)bparam)[lane];
    float4 acc = {0.f, 0.f, 0.f, 0.f};
    for (int it = 0; it < 16; it++) {
        int t = it * 4 + w;
        size_t row = ((size_t)(b * 56 + ai * 8 + (t >> 3))) * 56 + aj * 8 + (t & 7);
        float4 v = ((const float4*)(x + row * CDIM))[lane];
        float s = v.x + v.y + v.z + v.w;
        float s2 = v.x * v.x + v.y * v.y + v.z * v.z + v.w * v.w;
#pragma unroll
        for (int off = 32; off; off >>= 1) {
            s += __shfl_xor(s, off, 64);
            s2 += __shfl_xor(s2, off, 64);
        }
        float mu = s * (1.0f / CDIM);
        float rstd = rsqrtf(s2 * (1.0f / CDIM) - mu * mu + 1e-5f);
        acc.x += (v.x - mu) * rstd * gv.x + bv.x;
        acc.y += (v.y - mu) * rstd * gv.y + bv.y;
        acc.z += (v.z - mu) * rstd * gv.z + bv.z;
        acc.w += (v.w - mu) * rstd * gv.w + bv.w;
    }
    __shared__ float red[4][CDIM];
    *(float4*)&red[w][lane * 4] = acc;
    __syncthreads();
    if (w == 0) {
        float4 r0 = *(float4*)&red[0][lane * 4];
        float4 r1 = *(float4*)&red[1][lane * 4];
        float4 r2 = *(float4*)&red[2][lane * 4];
        float4 r3 = *(float4*)&red[3][lane * 4];
        float4 o;
        o.x = (r0.x + r1.x + r2.x + r3.x) * (1.0f / 64.0f);
        o.y = (r0.y + r1.y + r2.y + r3.y) * (1.0f / 64.0f);
        o.z = (r0.z + r1.z + r2.z + r3.z) * (1.0f / 64.0f);
        o.w = (r0.w + r1.w + r2.w + r3.w) * (1.0f / 64.0f);
        *(float4*)(ymean + (size_t)blk * CDIM + lane * 4) = o;
    }
}

// ---------------- f32 projection of region means: qreg/kreg ----------------
__global__ __launch_bounds__(256) void regproj_kernel(const float* __restrict__ ymean,
                                                      const float* __restrict__ wqkv,
                                                      const float* __restrict__ bqkv,
                                                      float* __restrict__ qreg,
                                                      float* __restrict__ kreg) {
    int blk = blockIdx.x;
    __shared__ float ym[CDIM];
    ym[threadIdx.x] = ymean[(size_t)blk * CDIM + threadIdx.x];
    __syncthreads();
    int c = threadIdx.x;
    float sq = 0.f, sk = 0.f;
    for (int k = 0; k < CDIM; k++) {
        float yv = ym[k];
        sq = fmaf(yv, wqkv[(size_t)k * QKVDIM + c], sq);
        sk = fmaf(yv, wqkv[(size_t)k * QKVDIM + CDIM + c], sk);
    }
    qreg[(size_t)blk * CDIM + c] = sq + bqkv[c];
    kreg[(size_t)blk * CDIM + c] = sk + bqkv[CDIM + c];
}

// ---------------- weight transpose: f32 [K][N] -> bf16 [N][K] ----------------
__global__ __launch_bounds__(256) void wtrans_kernel(const float* __restrict__ src,
                                                     ushort_t* __restrict__ dst,
                                                     int K, int N) {
    __shared__ float t[32][33];
    int tx = threadIdx.x & 31, ty = threadIdx.x >> 5;
    int n0 = blockIdx.x * 32, k0 = blockIdx.y * 32;
#pragma unroll
    for (int i = 0; i < 4; i++) t[ty + i * 8][tx] = src[(size_t)(k0 + ty + i * 8) * N + n0 + tx];
    __syncthreads();
#pragma unroll
    for (int i = 0; i < 4; i++)
        dst[(size_t)(n0 + ty + i * 8) * K + k0 + tx] = bfr(t[tx][ty + i * 8]);
}

// ---------------- v^T: bf16 qkv v-slice -> vt [b][c=256][t=3136] ----------------
__global__ __launch_bounds__(256) void vtrans_kernel(const ushort_t* __restrict__ qkvbf,
                                                     ushort_t* __restrict__ vt) {
    __shared__ ushort_t t[32][34];
    int tx = threadIdx.x & 31, ty = threadIdx.x >> 5;
    int t0 = blockIdx.x * 32, c0 = blockIdx.y * 32, b = blockIdx.z;
#pragma unroll
    for (int i = 0; i < 4; i++)
        t[ty + i * 8][tx] = qkvbf[((size_t)b * 3136 + t0 + ty + i * 8) * QKVDIM + 512 + c0 + tx];
    __syncthreads();
#pragma unroll
    for (int i = 0; i < 4; i++)
        vt[((size_t)b * CDIM + c0 + ty + i * 8) * 3136 + t0 + tx] = t[tx][ty + i * 8];
}

// ---------------- bf16 MFMA GEMM, triple-buffered BK=32 (prefetch depth 2) ------
// XCD-bijective block swizzle. LDS swizzle: 16B slot ^= (row>>1)&3, both sides.
// Counted vmcnt: 2L in steady state (2 stages in flight), L / 0 only in tail.
// MODE 0: out bf16 [M][768], cols<256 scaled (LDS-staged stores)
// MODE 1/3: out f32 = v + bias + res (direct)
// MODE 2: out bf16 = gelu(v + bias) (LDS-staged stores)
template <int BM, int BN, int MODE>
__global__ __launch_bounds__(256) void mgemm(const ushort_t* __restrict__ A,
                                             const ushort_t* __restrict__ WT,
                                             const float* __restrict__ bias,
                                             const float* __restrict__ res,
                                             float* __restrict__ outf,
                                             ushort_t* __restrict__ outb,
                                             int N, int K) {
    constexpr int WM = BM / 2, WN = BN / 2, MI = WM / 16, NI = WN / 16;
    constexpr int RA = BM / 64, RB = BN / 64, L = RA + RB;
    constexpr int BUFB = (BM + BN) * 64;  // bytes per pipeline buffer
    __shared__ __align__(16) char smem[3 * BUFB];
    ushort_t* Cs = (ushort_t*)smem;  // epilogue staging (64 x 136), aliases buffers
    const int tid = threadIdx.x, lane = tid & 63, w = tid >> 6;
    const int wm = w >> 1, wn = w & 1;

    // XCD-bijective chunked swizzle (nwg % 8 == 0 for all our grids)
    const int gx = gridDim.x;
    const int nwg = gx * gridDim.y;
    const int bid = blockIdx.y * gx + blockIdx.x;
    const int lbid = (bid & 7) * (nwg >> 3) + (bid >> 3);
    const int tm = (lbid / gx) * BM, tn = (lbid % gx) * BN;

    f32x4 acc[MI][NI];
#pragma unroll
    for (int i = 0; i < MI; i++)
#pragma unroll
        for (int j = 0; j < NI; j++) acc[i][j] = (f32x4){0.f, 0.f, 0.f, 0.f};

    // hoisted per-lane stage addresses (element offset sans k0) and LDS dests (bytes)
    size_t aoff[RA], boff[RB];
    int adst[RA], bdst[RB];
#pragma unroll
    for (int p = 0; p < RA; p++) {
        int row = (p * 4 + w) * 16 + (lane >> 2);
        int slot = lane & 3;
        int mr = (row >> 1) & 3;
        aoff[p] = (size_t)(tm + row) * K + ((slot ^ mr) * 8);
        adst[p] = (p * 4 + w) * 1024;
    }
#pragma unroll
    for (int p = 0; p < RB; p++) {
        int row = (p * 4 + w) * 16 + (lane >> 2);
        int slot = lane & 3;
        int mr = (row >> 1) & 3;
        boff[p] = (size_t)(tn + row) * K + ((slot ^ mr) * 8);
        bdst[p] = BM * 64 + (p * 4 + w) * 1024;
    }
    // hoisted LDS read byte-offsets
    const int fr = lane & 15, sl = lane >> 4;
    int roa[MI], rob[NI];
#pragma unroll
    for (int i = 0; i < MI; i++) {
        int rowa = wm * WM + i * 16 + fr;
        roa[i] = rowa * 64 + ((sl ^ ((rowa >> 1) & 3)) * 16);
    }
#pragma unroll
    for (int j = 0; j < NI; j++) {
        int rowb = wn * WN + j * 16 + fr;
        rob[j] = BM * 64 + rowb * 64 + ((sl ^ ((rowb >> 1) & 3)) * 16);
    }

    auto stage = [&](int buf, int k0) {
        char* base = smem + buf * BUFB;
#pragma unroll
        for (int p = 0; p < RA; p++) glds16(A + aoff[p] + k0, base + adst[p]);
#pragma unroll
        for (int p = 0; p < RB; p++) glds16(WT + boff[p] + k0, base + bdst[p]);
    };

    const int NT = K >> 5;  // >= 8 for all our shapes
    stage(0, 0);
    stage(1, 32);
    int cb = 0, sb = 2;
    for (int kt = 0; kt < NT; ++kt) {
        if (kt + 2 < NT) {
            stage(sb, (kt + 2) * 32);
            sb = (sb + 1 < 3) ? sb + 1 : 0;
            waitvm<2 * L>();        // 2 stages in flight; oldest (this iter's) done
        } else if (kt + 1 < NT) {
            waitvm<L>();
        } else {
            waitvm<0>();
        }
        barrier_raw();
        const char* base = smem + cb * BUFB;
        s16x8 af[MI], bfv[NI];
#pragma unroll
        for (int i = 0; i < MI; i++) af[i] = *(const s16x8*)(base + roa[i]);
#pragma unroll
        for (int j = 0; j < NI; j++) bfv[j] = *(const s16x8*)(base + rob[j]);
#pragma unroll
        for (int i = 0; i < MI; i++)
#pragma unroll
            for (int j = 0; j < NI; j++)
                acc[i][j] = __builtin_amdgcn_mfma_f32_16x16x32_bf16(af[i], bfv[j], acc[i][j], 0, 0, 0);
        barrier_raw();
        cb = (cb + 1 < 3) ? cb + 1 : 0;
    }

    const int cl = lane & 15, gq = lane >> 4;
    if constexpr (MODE == 0 || MODE == 2) {
        // LDS-staged epilogue: two 64-row phases; 16B contiguous stores. (BN == 128)
#pragma unroll
        for (int hh = 0; hh < 2; hh++) {
            if (wm == hh) {
#pragma unroll
                for (int j = 0; j < NI; j++) {
                    int lcol = wn * WN + j * 16 + cl;
                    int col = tn + lcol;
                    float bb = bias[col];
#pragma unroll
                    for (int i = 0; i < MI; i++) {
#pragma unroll
                        for (int r = 0; r < 4; r++) {
                            float v = acc[i][j][r] + bb;
                            ushort_t ov;
                            if (MODE == 0)
                                ov = bfr(col < 256 ? v * 0.17677669529663687f : v);
                            else
                                ov = bfr(gelu_f(v));
                            Cs[(i * 16 + gq * 4 + r) * 136 + lcol] = ov;
                        }
                    }
                }
            }
            __syncthreads();
            {
                int row_l = tid >> 2;         // 0..63
                int cbx = (tid & 3) * 8;      // 4 lanes cover 32 cols = 64B
                ushort_t* gbase = outb + (size_t)(tm + hh * 64 + row_l) * N + tn;
#pragma unroll
                for (int c = 0; c < 4; c++) {
                    int col = cbx + c * 32;
                    *(s16x8*)(gbase + col) = *(const s16x8*)&Cs[row_l * 136 + col];
                }
            }
            if (hh == 0) __syncthreads();
        }
    } else {
#pragma unroll
        for (int j = 0; j < NI; j++) {
            int col = tn + wn * WN + j * 16 + cl;
            float bb = bias[col];
#pragma unroll
            for (int i = 0; i < MI; i++) {
                int rowb = tm + wm * WM + i * 16 + gq * 4;
#pragma unroll
                for (int r = 0; r < 4; r++) {
                    float v = acc[i][j][r] + bb;
                    size_t off = (size_t)(rowb + r) * N + col;
                    outf[off] = v + res[off];
                }
            }
        }
    }
}

// ---------------- routing top-4 (set) ----------------
__global__ __launch_bounds__(64) void routing_kernel(const float* __restrict__ qreg,
                                                     const float* __restrict__ kreg,
                                                     int* __restrict__ idx) {
    int b = blockIdx.x / NREG;
    int row = blockIdx.x % NREG;
    int lane = threadIdx.x;
    float myv = -INFINITY;
    if (lane < NREG) {
        const float* qv = qreg + ((size_t)b * NREG + row) * CDIM;
        const float* kv = kreg + ((size_t)b * NREG + lane) * CDIM;
        float s = 0.f;
        for (int c = 0; c < CDIM; c++) s += qv[c] * kv[c];
        myv = s;
    }
    for (int t = 0; t < TK; t++) {
        float v = myv;
        int ix = lane;
#pragma unroll
        for (int off = 32; off; off >>= 1) {
            float ov = __shfl_xor(v, off, 64);
            int oi = __shfl_xor(ix, off, 64);
            if (ov > v || (ov == v && oi < ix)) { v = ov; ix = oi; }
        }
        if (lane == 0) idx[((size_t)b * NREG + row) * TK + t] = ix;
        if (lane == ix) myv = -INFINITY;
    }
}

// ---------------- MFMA flash attention, fully in-register ----------------
__global__ __launch_bounds__(256) void attn2_kernel(const ushort_t* __restrict__ qk,
                                                    const ushort_t* __restrict__ vt,
                                                    const int* __restrict__ idx,
                                                    ushort_t* __restrict__ outb) {
    int wid = blockIdx.x * 4 + (threadIdx.x >> 6);
    int lane = threadIdx.x & 63;
    int g = lane >> 5, col = lane & 31;
    int qh = wid & 1;
    int h = (wid >> 1) & 7;
    int rr = wid >> 4;  // b*49 + rid
    int rid = rr % NREG, b = rr / NREG;
    int ai = rid / NWIN, aj = rid % NWIN;

    int qtok = qh * 32 + col;
    size_t qrow_g = ((size_t)(b * 56 + ai * 8 + (qtok >> 3))) * 56 + aj * 8 + (qtok & 7);
    const s16x8 bq0 = *(const s16x8*)(qk + qrow_g * QKVDIM + h * 32 + g * 8);
    const s16x8 bq1 = *(const s16x8*)(qk + qrow_g * QKVDIM + h * 32 + 16 + g * 8);

    const int* ip = idx + (size_t)rr * TK;
    int regs[4] = {ip[0], ip[1], ip[2], ip[3]};

    float m_run = -1e30f, l_run = 0.f;
    f32x16 o = zero16();
    const size_t vtrowbase = ((size_t)(b * CDIM + h * 32 + col)) * 3136;

#pragma unroll
    for (int rc = 0; rc < 4; rc++) {
        int reg = regs[rc];
        int rai = reg / NWIN, raj = reg % NWIN;
        s16x8 ka[2][2];
#pragma unroll
        for (int mf = 0; mf < 2; mf++) {
            int ktok = mf * 32 + col;
            size_t krow_g = ((size_t)(b * 56 + rai * 8 + (ktok >> 3))) * 56 + raj * 8 + (ktok & 7);
#pragma unroll
            for (int kd = 0; kd < 2; kd++)
                ka[mf][kd] = *(const s16x8*)(qk + krow_g * QKVDIM + 256 + h * 32 + kd * 16 + g * 8);
        }
        f32x16 s0 = zero16(), s1 = zero16();
        s0 = __builtin_amdgcn_mfma_f32_32x32x16_bf16(ka[0][0], bq0, s0, 0, 0, 0);
        s0 = __builtin_amdgcn_mfma_f32_32x32x16_bf16(ka[0][1], bq1, s0, 0, 0, 0);
        s1 = __builtin_amdgcn_mfma_f32_32x32x16_bf16(ka[1][0], bq0, s1, 0, 0, 0);
        s1 = __builtin_amdgcn_mfma_f32_32x32x16_bf16(ka[1][1], bq1, s1, 0, 0, 0);

        float tmax = -1e30f;
#pragma unroll
        for (int i = 0; i < 16; i++) tmax = fmaxf(tmax, fmaxf(s0[i], s1[i]));
        tmax = fmaxf(tmax, __shfl_xor(tmax, 32, 64));

        float m_new = fmaxf(m_run, tmax);
        float f = __expf(m_run - m_new);
        l_run *= f;
#pragma unroll
        for (int r = 0; r < 16; r++) {
            int orow = (r & 3) + 8 * (r >> 2) + 4 * g;
            float fr2 = __shfl(f, orow, 64);
            o[r] *= fr2;
        }
        m_run = m_new;

        float tsum = 0.f;
#pragma unroll
        for (int i = 0; i < 16; i++) {
            s0[i] = __expf(s0[i] - m_run);
            s1[i] = __expf(s1[i] - m_run);
            tsum += s0[i] + s1[i];
        }
        l_run += tsum + __shfl_xor(tsum, 32, 64);

#define PVSTEP(SS, CC, KS)                                                              \
    {                                                                                   \
        unsigned wa = (unsigned)bfr(SS[CC * 8 + 0]) | ((unsigned)bfr(SS[CC * 8 + 1]) << 16); \
        unsigned wb_ = (unsigned)bfr(SS[CC * 8 + 2]) | ((unsigned)bfr(SS[CC * 8 + 3]) << 16); \
        unsigned wc = (unsigned)bfr(SS[CC * 8 + 4]) | ((unsigned)bfr(SS[CC * 8 + 5]) << 16); \
        unsigned wd = (unsigned)bfr(SS[CC * 8 + 6]) | ((unsigned)bfr(SS[CC * 8 + 7]) << 16); \
        unsigned sxa = (unsigned)__shfl_xor((int)wa, 32, 64);                           \
        unsigned sxb = (unsigned)__shfl_xor((int)wb_, 32, 64);                          \
        unsigned sxc = (unsigned)__shfl_xor((int)wc, 32, 64);                           \
        unsigned sxd = (unsigned)__shfl_xor((int)wd, 32, 64);                           \
        U4 pw;                                                                          \
        pw.u[0] = g ? sxc : wa;                                                         \
        pw.u[1] = g ? sxd : wb_;                                                        \
        pw.u[2] = g ? wc : sxa;                                                         \
        pw.u[3] = g ? wd : sxb;                                                         \
        const s16x8 vb = *(const s16x8*)(vt + vtrowbase + (size_t)(rai * 8 + KS * 2 + g) * 56 + raj * 8); \
        o = __builtin_amdgcn_mfma_f32_32x32x16_bf16(pw.v, vb, o, 0, 0, 0);              \
    }
        PVSTEP(s0, 0, 0)
        PVSTEP(s0, 1, 1)
        PVSTEP(s1, 0, 2)
        PVSTEP(s1, 1, 3)
#undef PVSTEP
    }

#pragma unroll
    for (int r = 0; r < 16; r++) {
        int orow = (r & 3) + 8 * (r >> 2) + 4 * g;
        float lr = __shfl(l_run, orow, 64);
        float val = o[r] / lr;
        int tok = qh * 32 + orow;
        size_t row_g = ((size_t)(b * 56 + ai * 8 + (tok >> 3))) * 56 + aj * 8 + (tok & 7);
        outb[row_g * 256 + h * 32 + col] = bfr(val);
    }
}

extern "C" void kernel_launch(void* const* d_in, const int* in_sizes, int n_in,
                              void* d_out, int out_size, void* d_ws, size_t ws_size,
                              hipStream_t stream) {
    const float* x    = (const float*)d_in[0];
    const float* ln1g = (const float*)d_in[1];
    const float* ln1b = (const float*)d_in[2];
    const float* wqkv = (const float*)d_in[3];
    const float* bqkv = (const float*)d_in[4];
    const float* wo   = (const float*)d_in[5];
    const float* bo   = (const float*)d_in[6];
    const float* ln2g = (const float*)d_in[7];
    const float* ln2b = (const float*)d_in[8];
    const float* w1   = (const float*)d_in[9];
    const float* bm1  = (const float*)d_in[10];
    const float* w2   = (const float*)d_in[11];
    const float* bm2  = (const float*)d_in[12];
    float* out = (float*)d_out;
    char* ws = (char*)d_ws;

    // workspace layout (bytes), total ~131 MB:
    ushort_t* ws_qkvbf = (ushort_t*)(ws);                  // 38,535,168  [25088][768]
    ushort_t* ws_hbf   = (ushort_t*)(ws + 38535168);       // 51,380,224  [25088][1024]
    ushort_t* ws_ybf   = (ushort_t*)(ws + 89915392);       // 12,845,056  [25088][256]
    ushort_t* ws_vt    = (ushort_t*)(ws + 102760448);      // 12,845,056  [8][256][3136]
    ushort_t* ws_attn  = (ushort_t*)(ws + 115605504);      // 12,845,056  [25088][256]
    float*    ws_ymean = (float*)(ws + 128450560);         // 401,408
    float*    ws_qreg  = (float*)(ws + 128851968);         // 401,408
    float*    ws_kreg  = (float*)(ws + 129253376);         // 401,408
    int*      ws_idx   = (int*)(ws + 129654784);           // 6,272
    ushort_t* ws_wqkvT = (ushort_t*)(ws + 129661056);      // 393,216
    ushort_t* ws_woT   = (ushort_t*)(ws + 130054272);      // 131,072
    ushort_t* ws_w1T   = (ushort_t*)(ws + 130185344);      // 524,288
    ushort_t* ws_w2T   = (ushort_t*)(ws + 130709632);      // 524,288

    const int M = NROWS;

    // 0) weights -> bf16 transposed
    wtrans_kernel<<<dim3(768 / 32, 256 / 32), 256, 0, stream>>>(wqkv, ws_wqkvT, 256, 768);
    wtrans_kernel<<<dim3(256 / 32, 256 / 32), 256, 0, stream>>>(wo, ws_woT, 256, 256);
    wtrans_kernel<<<dim3(1024 / 32, 256 / 32), 256, 0, stream>>>(w1, ws_w1T, 256, 1024);
    wtrans_kernel<<<dim3(256 / 32, 1024 / 32), 256, 0, stream>>>(w2, ws_w2T, 1024, 256);
    // 1) y = LN1(x) -> bf16
    ln_kernel<<<M / 4, 256, 0, stream>>>(x, ln1g, ln1b, ws_ybf);
    // 2) routing path, all f32
    ymean_kernel<<<8 * NREG, 256, 0, stream>>>(x, ln1g, ln1b, ws_ymean);
    regproj_kernel<<<8 * NREG, 256, 0, stream>>>(ws_ymean, wqkv, bqkv, ws_qreg, ws_kreg);
    routing_kernel<<<8 * NREG, 64, 0, stream>>>(ws_qreg, ws_kreg, ws_idx);
    // 3) qkv = y @ wqkv + bqkv -> bf16 [M][768], q pre-scaled   (grid 1176)
    mgemm<128, 128, 0><<<dim3(QKVDIM / 128, M / 128), 256, 0, stream>>>(
        ws_ybf, ws_wqkvT, bqkv, nullptr, nullptr, ws_qkvbf, QKVDIM, CDIM);
    // 4) v^T (bf16, [b][c][3136])
    vtrans_kernel<<<dim3(3136 / 32, 256 / 32, 8), 256, 0, stream>>>(ws_qkvbf, ws_vt);
    // 5) attention -> bf16
    attn2_kernel<<<8 * NREG * NHEADS * 2 / 4, 256, 0, stream>>>(ws_qkvbf, ws_vt, ws_idx, ws_attn);
    // 6) x1 = x + attn @ wo + bo  (f32, into d_out)   (grid 784)
    mgemm<128, 64, 1><<<dim3(CDIM / 64, M / 128), 256, 0, stream>>>(
        ws_attn, ws_woT, bo, x, out, nullptr, CDIM, CDIM);
    // 7) z = LN2(x1) -> bf16
    ln_kernel<<<M / 4, 256, 0, stream>>>(out, ln2g, ln2b, ws_ybf);
    // 8) h = gelu(z @ w1 + bm1) -> bf16   (grid 1568)
    mgemm<128, 128, 2><<<dim3(1024 / 128, M / 128), 256, 0, stream>>>(
        ws_ybf, ws_w1T, bm1, nullptr, nullptr, ws_hbf, 1024, CDIM);
    // 9) out = x1 + h @ w2 + bm2 (f32, in-place residual from d_out)   (grid 784)
    mgemm<128, 64, 3><<<dim3(CDIM / 64, M / 128), 256, 0, stream>>>(
        ws_hbf, ws_w2T, bm2, out, out, nullptr, CDIM, 1024);
}